// Round 21
// baseline (169.109 us; speedup 1.0000x reference)
//
#include <hip/hip_runtime.h>
#include <hip/hip_fp16.h>

#define BB 4
#define CC 256
#define NN 4096
#define CNT (CC*NN)
#define VLD 40   // padded V row stride (ushorts): banks de-alias (80B rows)

typedef float f32x4 __attribute__((ext_vector_type(4)));
typedef short bf16x8 __attribute__((ext_vector_type(8)));

__device__ inline ushort f2bf(float f) {
    union { float f; uint u; } v; v.f = f;
    uint r = v.u + 0x7fff + ((v.u >> 16) & 1);
    return (ushort)(r >> 16);
}

__device__ inline ushort f2h(float f) {
    __half h = __float2half(f);
    return *(ushort*)&h;
}

__device__ inline float h2f(ushort u) {
    __half h = *(__half*)&u;
    return __half2float(h);
}

__device__ inline uint cvt_pk_bf16(float a, float b) {
    uint r;
    asm("v_cvt_pk_bf16_f32 %0, %1, %2" : "=v"(r) : "v"(a), "v"(b));
    return r;
}

#define MFMA16(d, a, b) d = __builtin_amdgcn_mfma_f32_16x16x32_bf16(a, b, d, 0, 0, 0)

// sigma: inverse of the PV contraction permutation pi (within a 32-token tile).
__device__ inline int sigma32(int j) {
    return (j < 16) ? (((j >> 2) << 3) + (j & 3))
                    : ((((j - 16) >> 2) << 3) + ((j - 16) & 3) + 4);
}

// ---------------- stats (y<4) + weight prep (y==4), fused ----------------
__global__ __launch_bounds__(256) void stats_prep(
    const float* __restrict__ x, float* __restrict__ part,
    const float* __restrict__ qkv_w, const float* __restrict__ proj_w,
    ushort* __restrict__ wq, ushort* __restrict__ wp)
{
    if (blockIdx.y == 4) {
        int tid = blockIdx.x * 256 + threadIdx.x;      // 0..16383
        #pragma unroll
        for (int k = 0; k < 4; k++) {
            int idx = tid + k * 16384;                 // 0..65535
            if (idx < 49152) {
                int row = (idx * 4) >> 8;
                float sc = (row < 256) ? 0.0625f * 1.4426950408889634f : 1.0f;
                f32x4 v = *(const f32x4*)(qkv_w + (size_t)idx * 4);
                ushort4 o;
                o.x = f2bf(v.x * sc); o.y = f2bf(v.y * sc);
                o.z = f2bf(v.z * sc); o.w = f2bf(v.w * sc);
                *(ushort4*)(wq + (size_t)idx * 4) = o;
            } else {
                int j = idx - 49152;
                f32x4 v = *(const f32x4*)(proj_w + (size_t)j * 4);
                ushort4 o;
                o.x = f2bf(v.x); o.y = f2bf(v.y); o.z = f2bf(v.z); o.w = f2bf(v.w);
                *(ushort4*)(wp + (size_t)j * 4) = o;
            }
        }
        return;
    }
    int b = blockIdx.y;
    const float* xb = x + b * CNT;
    float s = 0.f, q = 0.f;
    int base = (blockIdx.x * 256 + threadIdx.x) * 4;
    for (int i = base; i < CNT; i += 64 * 256 * 4) {
        f32x4 v = *(const f32x4*)(xb + i);
        s += (v.x + v.y) + (v.z + v.w);
        q += (v.x * v.x + v.y * v.y) + (v.z * v.z + v.w * v.w);
    }
    for (int off = 32; off; off >>= 1) {
        s += __shfl_down(s, off, 64);
        q += __shfl_down(q, off, 64);
    }
    __shared__ float red[8];
    int lane = threadIdx.x & 63, wv = threadIdx.x >> 6;
    if (!lane) { red[wv * 2] = s; red[wv * 2 + 1] = q; }
    __syncthreads();
    if (threadIdx.x == 0) {
        part[(b * 64 + blockIdx.x) * 2 + 0] = red[0] + red[2] + red[4] + red[6];
        part[(b * 64 + blockIdx.x) * 2 + 1] = red[1] + red[3] + red[5] + red[7];
    }
}

// ---------------- norm + transpose (final stats reduce inlined per block) ----------------
__global__ __launch_bounds__(256) void norm_t_kernel(
    const float* __restrict__ x, const float* __restrict__ gamma,
    const float* __restrict__ beta, const float* __restrict__ part,
    ushort* __restrict__ xn_t)
{
    int b = blockIdx.z;
    __shared__ float mv[2];
    if (threadIdx.x < 64) {
        float s = part[(b * 64 + threadIdx.x) * 2 + 0];
        float q = part[(b * 64 + threadIdx.x) * 2 + 1];
        for (int off = 32; off; off >>= 1) {
            s += __shfl_down(s, off, 64);
            q += __shfl_down(q, off, 64);
        }
        if (threadIdx.x == 0) {
            float mean = s * (1.0f / (float)CNT);
            float var = q * (1.0f / (float)CNT) - mean * mean;
            mv[0] = mean;
            mv[1] = rsqrtf(var + 1e-5f);
        }
    }
    __syncthreads();
    float mean = mv[0], rinv = mv[1];

    int n0 = blockIdx.x * 32, c0 = blockIdx.y * 32;
    __shared__ float tl[32][33];
    int tr = threadIdx.x >> 3;
    int tc4 = (threadIdx.x & 7) * 4;
    int c = c0 + tr;
    float gsc = gamma[c] * rinv;
    float bsc = beta[c] - mean * gsc;
    f32x4 v = *(const f32x4*)(x + ((b * CC + c) * NN + n0 + tc4));
    tl[tr][tc4 + 0] = v.x * gsc + bsc;
    tl[tr][tc4 + 1] = v.y * gsc + bsc;
    tl[tr][tc4 + 2] = v.z * gsc + bsc;
    tl[tr][tc4 + 3] = v.w * gsc + bsc;
    __syncthreads();
    int nr = threadIdx.x >> 3;
    int cg4 = (threadIdx.x & 7) * 4;
    ushort4 o;
    o.x = f2bf(tl[cg4 + 0][nr]);
    o.y = f2bf(tl[cg4 + 1][nr]);
    o.z = f2bf(tl[cg4 + 2][nr]);
    o.w = f2bf(tl[cg4 + 3][nr]);
    *(ushort4*)(xn_t + ((size_t)(b * NN + n0 + nr) * CC + c0 + cg4)) = o;
}

// ---------------- QKV GEMM: bf16 weights; V written PERMUTED (sigma within 32-tiles) ----------------
__global__ __launch_bounds__(256) void qkv_kernel(
    const ushort* __restrict__ xn_t, const ushort* __restrict__ wq,
    const float* __restrict__ qkv_b, ushort* __restrict__ q_t,
    ushort* __restrict__ k_t, ushort* __restrict__ v_g)
{
    int b = blockIdx.z;
    int i0 = blockIdx.y * 64;
    int t = threadIdx.x, w = t >> 6, l = t & 63, l15 = l & 15, g = l >> 4;
    __shared__ ushort b_lds[64 * 256];

    #pragma unroll
    for (int it = 0; it < 8; it++) {
        int cid = it * 256 + t;
        int rr = cid >> 5, cc = cid & 31;
        bf16x8 vv = *(const bf16x8*)(xn_t + ((size_t)(b * NN + i0 + rr) * CC + cc * 8));
        *(bf16x8*)(b_lds + rr * 256 + (cc ^ (rr & 7)) * 8) = vv;
    }
    __syncthreads();

    for (int ds = 0; ds < 6; ds++) {
        int d0 = blockIdx.x * 384 + ds * 64;
        int drow = d0 + w * 16 + l15;
        bf16x8 af[8];
        #pragma unroll
        for (int kk = 0; kk < 8; kk++)
            af[kk] = *(const bf16x8*)(wq + (size_t)drow * CC + kk * 32 + g * 8);

        f32x4 acc[4];
        #pragma unroll
        for (int it = 0; it < 4; it++) { f32x4 z = {0.f, 0.f, 0.f, 0.f}; acc[it] = z; }
        #pragma unroll
        for (int kk = 0; kk < 8; kk++) {
            int cc = kk * 4 + g;
            #pragma unroll
            for (int it = 0; it < 4; it++) {
                int il = it * 16 + l15;
                bf16x8 bf = *(const bf16x8*)(b_lds + il * 256 + (cc ^ (il & 7)) * 8);
                MFMA16(acc[it], af[kk], bf);
            }
        }
        int dbase = d0 + w * 16 + g * 4;
        f32x4 bias = *(const f32x4*)(qkv_b + dbase);
        float bs = (d0 < 256) ? 0.0625f * 1.4426950408889634f : 1.0f;
        #pragma unroll
        for (int it = 0; it < 4; it++) {
            int i = i0 + it * 16 + l15;
            if (d0 < 512) {
                ushort4 o;
                o.x = f2bf(acc[it][0] + bias[0] * bs);
                o.y = f2bf(acc[it][1] + bias[1] * bs);
                o.z = f2bf(acc[it][2] + bias[2] * bs);
                o.w = f2bf(acc[it][3] + bias[3] * bs);
                ushort* dst = (d0 < 256) ? q_t : k_t;
                int dl = dbase - ((d0 < 256) ? 0 : 256);
                *(ushort4*)(dst + ((size_t)(b * NN + i) * CC + dl)) = o;
            } else {
                int ip = (i & ~31) | sigma32(i & 31);
                #pragma unroll
                for (int e = 0; e < 4; e++)
                    v_g[(size_t)(b * CC + (dbase - 512 + e)) * NN + ip] = f2bf(acc[it][e] + bias[e]);
            }
        }
    }
}

// ---------------- flash attention: zero-shuffle PV, padded V LDS (80B rows) ----------------
__global__ __launch_bounds__(512, 2) void flash_kernel(
    const ushort* __restrict__ q_t, const ushort* __restrict__ k_t,
    const ushort* __restrict__ v_g, ushort* __restrict__ On,
    float* __restrict__ l_part, int segn, int S, int nwg)
{
    int bid = blockIdx.x;
    int L = (bid & 7) * (nwg >> 3) + (bid >> 3);   // bijective (nwg % 8 == 0)
    int i0 = (L & 15) * 256;
    int seg = (L >> 4) % S;
    int b = L / (16 * S);
    int jbase = seg * segn;
    int t = threadIdx.x, w = t >> 6, l = t & 63, l15 = l & 15, g = l >> 4;

    __shared__ ushort k_lds[2][32 * 256];   // [j][16B chunk ^ (j&7)]
    __shared__ ushort v_lds[2][256 * VLD];  // [c][16B chunk ^ s4(c)], 80B row pitch

    bf16x8 qf0[8], qf1[8];
    const ushort* qr0 = q_t + (size_t)(b * NN + i0 + w * 32 + l15) * CC + g * 8;
    #pragma unroll
    for (int kk = 0; kk < 8; kk++) qf0[kk] = *(const bf16x8*)(qr0 + kk * 32);
    const ushort* qr1 = qr0 + (size_t)16 * CC;
    #pragma unroll
    for (int kk = 0; kk < 8; kk++) qf1[kk] = *(const bf16x8*)(qr1 + kk * 32);

    f32x4 O0[16], O1[16];
    #pragma unroll
    for (int tc = 0; tc < 16; tc++) {
        f32x4 z = {0.f, 0.f, 0.f, 0.f};
        O0[tc] = z; O1[tc] = z;
    }
    float l0 = 0.f, l1 = 0.f;

    const ushort* kb = k_t + (size_t)b * NN * CC;
    const ushort* vb = v_g + (size_t)b * CC * NN;

    auto stage_tile = [&](int d, int jt) {
        bf16x8 kr[2], vr[2];
        #pragma unroll
        for (int is = 0; is < 2; is++) {
            int s = is * 512 + t;
            kr[is] = *(const bf16x8*)(kb + (size_t)(jt + (s >> 5)) * CC + (s & 31) * 8);
            vr[is] = *(const bf16x8*)(vb + (size_t)(s >> 2) * NN + jt + (s & 3) * 8);
        }
        #pragma unroll
        for (int is = 0; is < 2; is++) {
            int s = is * 512 + t;
            int jr = s >> 5, cc = s & 31;
            *(bf16x8*)((ushort*)k_lds[d] + jr * 256 + ((cc ^ (jr & 7)) * 8)) = kr[is];
            int cr = s >> 2, cv = s & 3;
            *(bf16x8*)((ushort*)v_lds[d] + cr * VLD + ((cv ^ ((cr ^ (cr >> 2)) & 3)) * 8)) = vr[is];
        }
    };

    stage_tile(0, jbase);
    int niter = segn >> 5;

    for (int it = 0; it < niter; it++) {
        int d = it & 1;
        __syncthreads();
        const ushort* kl = k_lds[d];
        const ushort* vl = v_lds[d];

        // S^T = K Q^T, 4 independent chains (2 jg x 2 rb) sharing bk loads.
        f32x4 s00 = {0.f, 0.f, 0.f, 0.f}, s01 = s00, s10 = s00, s11 = s00;
        {
            const ushort* krow = kl + l15 * 256;
            int xj = l15 & 7;
            #pragma unroll
            for (int kk = 0; kk < 8; kk++) {
                int off = ((kk * 4 + g) ^ xj) * 8;
                bf16x8 bk0 = *(const bf16x8*)(krow + off);
                bf16x8 bk1 = *(const bf16x8*)(krow + 16 * 256 + off);
                MFMA16(s00, bk0, qf0[kk]);
                MFMA16(s10, bk0, qf1[kk]);
                MFMA16(s01, bk1, qf0[kk]);
                MFMA16(s11, bk1, qf1[kk]);
            }
        }

        // softmax: p = exp2(S); pack P directly as A-fragment (permuted-V contraction)
        union { bf16x8 v; uint u[4]; } pa0, pa1;
        {
            float a0 = exp2f(s00[0]), a1 = exp2f(s00[1]);
            float a2 = exp2f(s00[2]), a3 = exp2f(s00[3]);
            float a4 = exp2f(s01[0]), a5 = exp2f(s01[1]);
            float a6 = exp2f(s01[2]), a7 = exp2f(s01[3]);
            l0 += ((a0 + a1) + (a2 + a3)) + ((a4 + a5) + (a6 + a7));
            pa0.u[0] = cvt_pk_bf16(a0, a1); pa0.u[1] = cvt_pk_bf16(a2, a3);
            pa0.u[2] = cvt_pk_bf16(a4, a5); pa0.u[3] = cvt_pk_bf16(a6, a7);
            float b0 = exp2f(s10[0]), b1 = exp2f(s10[1]);
            float b2 = exp2f(s10[2]), b3 = exp2f(s10[3]);
            float b4 = exp2f(s11[0]), b5 = exp2f(s11[1]);
            float b6 = exp2f(s11[2]), b7 = exp2f(s11[3]);
            l1 += ((b0 + b1) + (b2 + b3)) + ((b4 + b5) + (b6 + b7));
            pa1.u[0] = cvt_pk_bf16(b0, b1); pa1.u[1] = cvt_pk_bf16(b2, b3);
            pa1.u[2] = cvt_pk_bf16(b4, b5); pa1.u[3] = cvt_pk_bf16(b6, b7);
        }

        // O += P V^T: B-fragment = contiguous b128 (chunk g) of permuted V
        #pragma unroll
        for (int tc = 0; tc < 16; tc++) {
            int c = tc * 16 + l15;
            bf16x8 vf = *(const bf16x8*)(vl + c * VLD + ((g ^ ((c ^ (c >> 2)) & 3)) * 8));
            MFMA16(O0[tc], pa0.v, vf);
            MFMA16(O1[tc], pa1.v, vf);
        }

        if (it + 1 < niter) stage_tile(d ^ 1, jbase + (it + 1) * 32);
    }

    // l lives per (l15): reduce across the 4 g-groups
    l0 += __shfl_xor(l0, 16, 64); l1 += __shfl_xor(l1, 16, 64);
    l0 += __shfl_xor(l0, 32, 64); l1 += __shfl_xor(l1, 32, 64);

    size_t obase = (size_t)(seg * BB + b) * NN + i0;
    if (g == 0) {
        l_part[obase + w * 32 + l15] = l0;
        l_part[obase + w * 32 + 16 + l15] = l1;
    }
    #pragma unroll
    for (int e = 0; e < 4; e++) {
        int ro = w * 32 + g * 4 + e;
        float inv0 = 1.0f / __shfl(l0, g * 4 + e, 64);
        float inv1 = 1.0f / __shfl(l1, g * 4 + e, 64);
        ushort* orow0 = On + (obase + ro) * CC + l15;
        ushort* orow1 = On + (obase + ro + 16) * CC + l15;
        #pragma unroll
        for (int tc = 0; tc < 16; tc++) {
            orow0[tc * 16] = f2h(O0[tc][e] * inv0);
            orow1[tc * 16] = f2h(O1[tc][e] * inv1);
        }
    }
}

// ---------------- merge: out = (sum_s l_s * O_s_norm) / (sum_s l_s), fp16 in, bf16 out ----------------
__global__ __launch_bounds__(256) void merge_kernel(
    const ushort* __restrict__ On, const float* __restrict__ l_part,
    ushort* __restrict__ out_t, int S)
{
    int idx = blockIdx.x * 256 + threadIdx.x;
    int row = idx >> 6;
    float lsum = 0.f;
    float a0 = 0.f, a1 = 0.f, a2 = 0.f, a3 = 0.f;
    for (int s = 0; s < S; s++) {
        float ls = l_part[(size_t)s * BB * NN + row];
        lsum += ls;
        ushort4 v = *(const ushort4*)(On + (size_t)s * BB * NN * CC + (size_t)idx * 4);
        a0 += ls * h2f(v.x);
        a1 += ls * h2f(v.y);
        a2 += ls * h2f(v.z);
        a3 += ls * h2f(v.w);
    }
    float inv = 1.0f / lsum;
    ushort4 o;
    o.x = f2bf(a0 * inv);
    o.y = f2bf(a1 * inv);
    o.z = f2bf(a2 * inv);
    o.w = f2bf(a3 * inv);
    *(ushort4*)(out_t + (size_t)idx * 4) = o;
}

// ---------------- proj GEMM + bias + residual (bf16 weights) ----------------
__global__ __launch_bounds__(256) void proj_kernel(
    const ushort* __restrict__ out_t, const ushort* __restrict__ wp,
    const float* __restrict__ proj_b, const float* __restrict__ x,
    float* __restrict__ out)
{
    int b = blockIdx.z;
    int d0 = blockIdx.x * 64;
    int i0 = blockIdx.y * 256;
    int t = threadIdx.x, w = t >> 6, l = t & 63, l15 = l & 15, g = l >> 4;
    __shared__ ushort a_lds[64 * 256];

    #pragma unroll
    for (int it = 0; it < 8; it++) {
        int cid = it * 256 + t;
        int dd = cid >> 5, cc = cid & 31;
        bf16x8 a = *(const bf16x8*)(wp + (size_t)(d0 + dd) * CC + cc * 8);
        *(bf16x8*)(a_lds + dd * 256 + (cc ^ (dd & 7)) * 8) = a;
    }
    __syncthreads();

    f32x4 acc[16];
    #pragma unroll
    for (int it = 0; it < 16; it++) { f32x4 z = {0.f, 0.f, 0.f, 0.f}; acc[it] = z; }
    int dl = w * 16 + l15;
    #pragma unroll
    for (int kk = 0; kk < 8; kk++) {
        int cc = kk * 4 + g;
        bf16x8 af = *(const bf16x8*)(a_lds + dl * 256 + (cc ^ (dl & 7)) * 8);
        #pragma unroll
        for (int it = 0; it < 16; it++) {
            bf16x8 bfr = *(const bf16x8*)(out_t + (size_t)(b * NN + i0 + it * 16 + l15) * CC + kk * 32 + g * 8);
            MFMA16(acc[it], af, bfr);
        }
    }
    int dbase = d0 + w * 16 + g * 4;
    f32x4 pb = *(const f32x4*)(proj_b + dbase);
    #pragma unroll
    for (int it = 0; it < 16; it++) {
        int i = i0 + it * 16 + l15;
        #pragma unroll
        for (int e = 0; e < 4; e++) {
            int off = (b * CC + dbase + e) * NN + i;
            out[off] = acc[it][e] + pb[e] + x[off];
        }
    }
}

extern "C" void kernel_launch(void* const* d_in, const int* in_sizes, int n_in,
                              void* d_out, int out_size, void* d_ws, size_t ws_size,
                              hipStream_t stream) {
    const float* x      = (const float*)d_in[0];
    const float* gamma  = (const float*)d_in[1];
    const float* beta   = (const float*)d_in[2];
    const float* qkv_w  = (const float*)d_in[3];
    const float* qkv_b  = (const float*)d_in[4];
    const float* proj_w = (const float*)d_in[5];
    const float* proj_b = (const float*)d_in[6];
    float* out = (float*)d_out;

    char* ws = (char*)d_ws;
    float* part   = (float*)ws;                       // 2048 B
    ushort* wq    = (ushort*)(ws + 4096);             // 384 KiB
    ushort* wp    = (ushort*)(ws + 4096 + 393216);    // 128 KiB -> ends 528384
    ushort* xn_t  = (ushort*)(ws + 528384);
    ushort* q_t   = (ushort*)(ws + 528384 + 1ull * 8388608);
    ushort* k_t   = (ushort*)(ws + 528384 + 2ull * 8388608);
    ushort* v_g   = (ushort*)(ws + 528384 + 3ull * 8388608);
    ushort* out_t = xn_t;

    size_t mlbase = 528384 + 4ull * 8388608;
    float* l_part = (float*)(ws + mlbase);
    size_t obase  = mlbase + 1048576;
    ushort* On    = (ushort*)(ws + obase);            // S * 8 MiB (fp16 normalized)

    int S = 1;
    if (ws_size >= obase + 4ull * 8388608) S = 4;
    else if (ws_size >= obase + 2ull * 8388608) S = 2;
    int nwg = 16 * S * BB;

    stats_prep<<<dim3(64, 5), 256, 0, stream>>>(x, part, qkv_w, proj_w, wq, wp);
    norm_t_kernel<<<dim3(128, 8, 4), 256, 0, stream>>>(x, gamma, beta, part, xn_t);
    qkv_kernel<<<dim3(2, 64, 4), 256, 0, stream>>>(xn_t, wq, qkv_b, q_t, k_t, v_g);
    flash_kernel<<<nwg, 512, 0, stream>>>(q_t, k_t, v_g, On, l_part, NN / S, S, nwg);
    merge_kernel<<<4096, 256, 0, stream>>>(On, l_part, out_t, S);
    proj_kernel<<<dim3(4, 16, 4), 256, 0, stream>>>(out_t, wp, proj_b, x, out);
}

// Round 22
// 168.573 us; speedup vs baseline: 1.0032x; 1.0032x over previous
//
#include <hip/hip_runtime.h>
#include <hip/hip_fp16.h>

#define BB 4
#define CC 256
#define NN 4096
#define CNT (CC*NN)
#define VLD 40   // padded V row stride (ushorts): banks de-alias (80B rows)

typedef float f32x4 __attribute__((ext_vector_type(4)));
typedef short bf16x8 __attribute__((ext_vector_type(8)));

__device__ inline ushort f2bf(float f) {
    union { float f; uint u; } v; v.f = f;
    uint r = v.u + 0x7fff + ((v.u >> 16) & 1);
    return (ushort)(r >> 16);
}

__device__ inline ushort f2h(float f) {
    __half h = __float2half(f);
    return *(ushort*)&h;
}

__device__ inline float h2f(ushort u) {
    __half h = *(__half*)&u;
    return __half2float(h);
}

__device__ inline uint cvt_pk_bf16(float a, float b) {
    uint r;
    asm("v_cvt_pk_bf16_f32 %0, %1, %2" : "=v"(r) : "v"(a), "v"(b));
    return r;
}

#define MFMA16(d, a, b) d = __builtin_amdgcn_mfma_f32_16x16x32_bf16(a, b, d, 0, 0, 0)

// sigma: inverse of the PV contraction permutation pi (within a 32-token tile).
__device__ inline int sigma32(int j) {
    return (j < 16) ? (((j >> 2) << 3) + (j & 3))
                    : ((((j - 16) >> 2) << 3) + ((j - 16) & 3) + 4);
}

// ---------------- stats (y<4) + weight prep (y==4), fused ----------------
__global__ __launch_bounds__(256) void stats_prep(
    const float* __restrict__ x, float* __restrict__ part,
    const float* __restrict__ qkv_w, const float* __restrict__ proj_w,
    ushort* __restrict__ wq, ushort* __restrict__ wp)
{
    if (blockIdx.y == 4) {
        int tid = blockIdx.x * 256 + threadIdx.x;      // 0..16383
        #pragma unroll
        for (int k = 0; k < 4; k++) {
            int idx = tid + k * 16384;                 // 0..65535
            if (idx < 49152) {
                int row = (idx * 4) >> 8;
                float sc = (row < 256) ? 0.0625f * 1.4426950408889634f : 1.0f;
                f32x4 v = *(const f32x4*)(qkv_w + (size_t)idx * 4);
                ushort4 o;
                o.x = f2bf(v.x * sc); o.y = f2bf(v.y * sc);
                o.z = f2bf(v.z * sc); o.w = f2bf(v.w * sc);
                *(ushort4*)(wq + (size_t)idx * 4) = o;
            } else {
                int j = idx - 49152;
                f32x4 v = *(const f32x4*)(proj_w + (size_t)j * 4);
                ushort4 o;
                o.x = f2bf(v.x); o.y = f2bf(v.y); o.z = f2bf(v.z); o.w = f2bf(v.w);
                *(ushort4*)(wp + (size_t)j * 4) = o;
            }
        }
        return;
    }
    int b = blockIdx.y;
    const float* xb = x + b * CNT;
    float s = 0.f, q = 0.f;
    int base = (blockIdx.x * 256 + threadIdx.x) * 4;
    for (int i = base; i < CNT; i += 64 * 256 * 4) {
        f32x4 v = *(const f32x4*)(xb + i);
        s += (v.x + v.y) + (v.z + v.w);
        q += (v.x * v.x + v.y * v.y) + (v.z * v.z + v.w * v.w);
    }
    for (int off = 32; off; off >>= 1) {
        s += __shfl_down(s, off, 64);
        q += __shfl_down(q, off, 64);
    }
    __shared__ float red[8];
    int lane = threadIdx.x & 63, wv = threadIdx.x >> 6;
    if (!lane) { red[wv * 2] = s; red[wv * 2 + 1] = q; }
    __syncthreads();
    if (threadIdx.x == 0) {
        part[(b * 64 + blockIdx.x) * 2 + 0] = red[0] + red[2] + red[4] + red[6];
        part[(b * 64 + blockIdx.x) * 2 + 1] = red[1] + red[3] + red[5] + red[7];
    }
}

// ---------------- norm + transpose (final stats reduce inlined per block) ----------------
__global__ __launch_bounds__(256) void norm_t_kernel(
    const float* __restrict__ x, const float* __restrict__ gamma,
    const float* __restrict__ beta, const float* __restrict__ part,
    ushort* __restrict__ xn_t)
{
    int b = blockIdx.z;
    __shared__ float mv[2];
    if (threadIdx.x < 64) {
        float s = part[(b * 64 + threadIdx.x) * 2 + 0];
        float q = part[(b * 64 + threadIdx.x) * 2 + 1];
        for (int off = 32; off; off >>= 1) {
            s += __shfl_down(s, off, 64);
            q += __shfl_down(q, off, 64);
        }
        if (threadIdx.x == 0) {
            float mean = s * (1.0f / (float)CNT);
            float var = q * (1.0f / (float)CNT) - mean * mean;
            mv[0] = mean;
            mv[1] = rsqrtf(var + 1e-5f);
        }
    }
    __syncthreads();
    float mean = mv[0], rinv = mv[1];

    int n0 = blockIdx.x * 32, c0 = blockIdx.y * 32;
    __shared__ float tl[32][33];
    int tr = threadIdx.x >> 3;
    int tc4 = (threadIdx.x & 7) * 4;
    int c = c0 + tr;
    float gsc = gamma[c] * rinv;
    float bsc = beta[c] - mean * gsc;
    f32x4 v = *(const f32x4*)(x + ((b * CC + c) * NN + n0 + tc4));
    tl[tr][tc4 + 0] = v.x * gsc + bsc;
    tl[tr][tc4 + 1] = v.y * gsc + bsc;
    tl[tr][tc4 + 2] = v.z * gsc + bsc;
    tl[tr][tc4 + 3] = v.w * gsc + bsc;
    __syncthreads();
    int nr = threadIdx.x >> 3;
    int cg4 = (threadIdx.x & 7) * 4;
    ushort4 o;
    o.x = f2bf(tl[cg4 + 0][nr]);
    o.y = f2bf(tl[cg4 + 1][nr]);
    o.z = f2bf(tl[cg4 + 2][nr]);
    o.w = f2bf(tl[cg4 + 3][nr]);
    *(ushort4*)(xn_t + ((size_t)(b * NN + n0 + nr) * CC + c0 + cg4)) = o;
}

// ---------------- QKV GEMM: bf16 weights; V written PERMUTED (sigma within 32-tiles) ----------------
__global__ __launch_bounds__(256) void qkv_kernel(
    const ushort* __restrict__ xn_t, const ushort* __restrict__ wq,
    const float* __restrict__ qkv_b, ushort* __restrict__ q_t,
    ushort* __restrict__ k_t, ushort* __restrict__ v_g)
{
    int b = blockIdx.z;
    int i0 = blockIdx.y * 64;
    int t = threadIdx.x, w = t >> 6, l = t & 63, l15 = l & 15, g = l >> 4;
    __shared__ ushort b_lds[64 * 256];

    #pragma unroll
    for (int it = 0; it < 8; it++) {
        int cid = it * 256 + t;
        int rr = cid >> 5, cc = cid & 31;
        bf16x8 vv = *(const bf16x8*)(xn_t + ((size_t)(b * NN + i0 + rr) * CC + cc * 8));
        *(bf16x8*)(b_lds + rr * 256 + (cc ^ (rr & 7)) * 8) = vv;
    }
    __syncthreads();

    for (int ds = 0; ds < 6; ds++) {
        int d0 = blockIdx.x * 384 + ds * 64;
        int drow = d0 + w * 16 + l15;
        bf16x8 af[8];
        #pragma unroll
        for (int kk = 0; kk < 8; kk++)
            af[kk] = *(const bf16x8*)(wq + (size_t)drow * CC + kk * 32 + g * 8);

        f32x4 acc[4];
        #pragma unroll
        for (int it = 0; it < 4; it++) { f32x4 z = {0.f, 0.f, 0.f, 0.f}; acc[it] = z; }
        #pragma unroll
        for (int kk = 0; kk < 8; kk++) {
            int cc = kk * 4 + g;
            #pragma unroll
            for (int it = 0; it < 4; it++) {
                int il = it * 16 + l15;
                bf16x8 bf = *(const bf16x8*)(b_lds + il * 256 + (cc ^ (il & 7)) * 8);
                MFMA16(acc[it], af[kk], bf);
            }
        }
        int dbase = d0 + w * 16 + g * 4;
        f32x4 bias = *(const f32x4*)(qkv_b + dbase);
        float bs = (d0 < 256) ? 0.0625f * 1.4426950408889634f : 1.0f;
        #pragma unroll
        for (int it = 0; it < 4; it++) {
            int i = i0 + it * 16 + l15;
            if (d0 < 512) {
                ushort4 o;
                o.x = f2bf(acc[it][0] + bias[0] * bs);
                o.y = f2bf(acc[it][1] + bias[1] * bs);
                o.z = f2bf(acc[it][2] + bias[2] * bs);
                o.w = f2bf(acc[it][3] + bias[3] * bs);
                ushort* dst = (d0 < 256) ? q_t : k_t;
                int dl = dbase - ((d0 < 256) ? 0 : 256);
                *(ushort4*)(dst + ((size_t)(b * NN + i) * CC + dl)) = o;
            } else {
                int ip = (i & ~31) | sigma32(i & 31);
                #pragma unroll
                for (int e = 0; e < 4; e++)
                    v_g[(size_t)(b * CC + (dbase - 512 + e)) * NN + ip] = f2bf(acc[it][e] + bias[e]);
            }
        }
    }
}

// ---------------- flash attention: zero-shuffle PV, padded V LDS (80B rows) ----------------
__global__ __launch_bounds__(512, 2) void flash_kernel(
    const ushort* __restrict__ q_t, const ushort* __restrict__ k_t,
    const ushort* __restrict__ v_g, ushort* __restrict__ On,
    float* __restrict__ l_part, int segn, int S, int nwg)
{
    int bid = blockIdx.x;
    int L = (bid & 7) * (nwg >> 3) + (bid >> 3);   // bijective (nwg % 8 == 0)
    int i0 = (L & 15) * 256;
    int seg = (L >> 4) % S;
    int b = L / (16 * S);
    int jbase = seg * segn;
    int t = threadIdx.x, w = t >> 6, l = t & 63, l15 = l & 15, g = l >> 4;

    __shared__ ushort k_lds[2][32 * 256];   // [j][16B chunk ^ (j&7)]
    __shared__ ushort v_lds[2][256 * VLD];  // [c][16B chunk ^ s4(c)], 80B row pitch

    bf16x8 qf0[8], qf1[8];
    const ushort* qr0 = q_t + (size_t)(b * NN + i0 + w * 32 + l15) * CC + g * 8;
    #pragma unroll
    for (int kk = 0; kk < 8; kk++) qf0[kk] = *(const bf16x8*)(qr0 + kk * 32);
    const ushort* qr1 = qr0 + (size_t)16 * CC;
    #pragma unroll
    for (int kk = 0; kk < 8; kk++) qf1[kk] = *(const bf16x8*)(qr1 + kk * 32);

    f32x4 O0[16], O1[16];
    #pragma unroll
    for (int tc = 0; tc < 16; tc++) {
        f32x4 z = {0.f, 0.f, 0.f, 0.f};
        O0[tc] = z; O1[tc] = z;
    }
    float l0 = 0.f, l1 = 0.f;

    const ushort* kb = k_t + (size_t)b * NN * CC;
    const ushort* vb = v_g + (size_t)b * CC * NN;

    auto stage_tile = [&](int d, int jt) {
        bf16x8 kr[2], vr[2];
        #pragma unroll
        for (int is = 0; is < 2; is++) {
            int s = is * 512 + t;
            kr[is] = *(const bf16x8*)(kb + (size_t)(jt + (s >> 5)) * CC + (s & 31) * 8);
            vr[is] = *(const bf16x8*)(vb + (size_t)(s >> 2) * NN + jt + (s & 3) * 8);
        }
        #pragma unroll
        for (int is = 0; is < 2; is++) {
            int s = is * 512 + t;
            int jr = s >> 5, cc = s & 31;
            *(bf16x8*)((ushort*)k_lds[d] + jr * 256 + ((cc ^ (jr & 7)) * 8)) = kr[is];
            int cr = s >> 2, cv = s & 3;
            *(bf16x8*)((ushort*)v_lds[d] + cr * VLD + ((cv ^ ((cr ^ (cr >> 2)) & 3)) * 8)) = vr[is];
        }
    };

    stage_tile(0, jbase);
    int niter = segn >> 5;

    for (int it = 0; it < niter; it++) {
        int d = it & 1;
        __syncthreads();
        const ushort* kl = k_lds[d];
        const ushort* vl = v_lds[d];

        // S^T = K Q^T, 4 independent chains (2 jg x 2 rb) sharing bk loads.
        f32x4 s00 = {0.f, 0.f, 0.f, 0.f}, s01 = s00, s10 = s00, s11 = s00;
        {
            const ushort* krow = kl + l15 * 256;
            int xj = l15 & 7;
            #pragma unroll
            for (int kk = 0; kk < 8; kk++) {
                int off = ((kk * 4 + g) ^ xj) * 8;
                bf16x8 bk0 = *(const bf16x8*)(krow + off);
                bf16x8 bk1 = *(const bf16x8*)(krow + 16 * 256 + off);
                MFMA16(s00, bk0, qf0[kk]);
                MFMA16(s10, bk0, qf1[kk]);
                MFMA16(s01, bk1, qf0[kk]);
                MFMA16(s11, bk1, qf1[kk]);
            }
        }

        // softmax: p = exp2(S); pack P directly as A-fragment (permuted-V contraction)
        union { bf16x8 v; uint u[4]; } pa0, pa1;
        {
            float a0 = exp2f(s00[0]), a1 = exp2f(s00[1]);
            float a2 = exp2f(s00[2]), a3 = exp2f(s00[3]);
            float a4 = exp2f(s01[0]), a5 = exp2f(s01[1]);
            float a6 = exp2f(s01[2]), a7 = exp2f(s01[3]);
            l0 += ((a0 + a1) + (a2 + a3)) + ((a4 + a5) + (a6 + a7));
            pa0.u[0] = cvt_pk_bf16(a0, a1); pa0.u[1] = cvt_pk_bf16(a2, a3);
            pa0.u[2] = cvt_pk_bf16(a4, a5); pa0.u[3] = cvt_pk_bf16(a6, a7);
            float b0 = exp2f(s10[0]), b1 = exp2f(s10[1]);
            float b2 = exp2f(s10[2]), b3 = exp2f(s10[3]);
            float b4 = exp2f(s11[0]), b5 = exp2f(s11[1]);
            float b6 = exp2f(s11[2]), b7 = exp2f(s11[3]);
            l1 += ((b0 + b1) + (b2 + b3)) + ((b4 + b5) + (b6 + b7));
            pa1.u[0] = cvt_pk_bf16(b0, b1); pa1.u[1] = cvt_pk_bf16(b2, b3);
            pa1.u[2] = cvt_pk_bf16(b4, b5); pa1.u[3] = cvt_pk_bf16(b6, b7);
        }

        // O += P V^T: B-fragment = contiguous b128 (chunk g) of permuted V
        #pragma unroll
        for (int tc = 0; tc < 16; tc++) {
            int c = tc * 16 + l15;
            bf16x8 vf = *(const bf16x8*)(vl + c * VLD + ((g ^ ((c ^ (c >> 2)) & 3)) * 8));
            MFMA16(O0[tc], pa0.v, vf);
            MFMA16(O1[tc], pa1.v, vf);
        }

        if (it + 1 < niter) stage_tile(d ^ 1, jbase + (it + 1) * 32);
    }

    // l lives per (l15): reduce across the 4 g-groups
    l0 += __shfl_xor(l0, 16, 64); l1 += __shfl_xor(l1, 16, 64);
    l0 += __shfl_xor(l0, 32, 64); l1 += __shfl_xor(l1, 32, 64);

    size_t obase = (size_t)(seg * BB + b) * NN + i0;
    if (g == 0) {
        l_part[obase + w * 32 + l15] = l0;
        l_part[obase + w * 32 + 16 + l15] = l1;
    }
    #pragma unroll
    for (int e = 0; e < 4; e++) {
        int ro = w * 32 + g * 4 + e;
        float inv0 = 1.0f / __shfl(l0, g * 4 + e, 64);
        float inv1 = 1.0f / __shfl(l1, g * 4 + e, 64);
        ushort* orow0 = On + (obase + ro) * CC + l15;
        ushort* orow1 = On + (obase + ro + 16) * CC + l15;
        #pragma unroll
        for (int tc = 0; tc < 16; tc++) {
            orow0[tc * 16] = f2h(O0[tc][e] * inv0);
            orow1[tc * 16] = f2h(O1[tc][e] * inv1);
        }
    }
}

// ---------------- merge: out = (sum_s l_s * O_s_norm) / (sum_s l_s), fp16 in, bf16 out ----------------
__global__ __launch_bounds__(256) void merge_kernel(
    const ushort* __restrict__ On, const float* __restrict__ l_part,
    ushort* __restrict__ out_t, int S)
{
    int idx = blockIdx.x * 256 + threadIdx.x;
    int row = idx >> 6;
    float lsum = 0.f;
    float a0 = 0.f, a1 = 0.f, a2 = 0.f, a3 = 0.f;
    for (int s = 0; s < S; s++) {
        float ls = l_part[(size_t)s * BB * NN + row];
        lsum += ls;
        ushort4 v = *(const ushort4*)(On + (size_t)s * BB * NN * CC + (size_t)idx * 4);
        a0 += ls * h2f(v.x);
        a1 += ls * h2f(v.y);
        a2 += ls * h2f(v.z);
        a3 += ls * h2f(v.w);
    }
    float inv = 1.0f / lsum;
    ushort4 o;
    o.x = f2bf(a0 * inv);
    o.y = f2bf(a1 * inv);
    o.z = f2bf(a2 * inv);
    o.w = f2bf(a3 * inv);
    *(ushort4*)(out_t + (size_t)idx * 4) = o;
}

// ---------------- proj GEMM + bias + residual (bf16 weights) ----------------
__global__ __launch_bounds__(256) void proj_kernel(
    const ushort* __restrict__ out_t, const ushort* __restrict__ wp,
    const float* __restrict__ proj_b, const float* __restrict__ x,
    float* __restrict__ out)
{
    int b = blockIdx.z;
    int d0 = blockIdx.x * 64;
    int i0 = blockIdx.y * 256;
    int t = threadIdx.x, w = t >> 6, l = t & 63, l15 = l & 15, g = l >> 4;
    __shared__ ushort a_lds[64 * 256];

    #pragma unroll
    for (int it = 0; it < 8; it++) {
        int cid = it * 256 + t;
        int dd = cid >> 5, cc = cid & 31;
        bf16x8 a = *(const bf16x8*)(wp + (size_t)(d0 + dd) * CC + cc * 8);
        *(bf16x8*)(a_lds + dd * 256 + (cc ^ (dd & 7)) * 8) = a;
    }
    __syncthreads();

    f32x4 acc[16];
    #pragma unroll
    for (int it = 0; it < 16; it++) { f32x4 z = {0.f, 0.f, 0.f, 0.f}; acc[it] = z; }
    int dl = w * 16 + l15;
    #pragma unroll
    for (int kk = 0; kk < 8; kk++) {
        int cc = kk * 4 + g;
        bf16x8 af = *(const bf16x8*)(a_lds + dl * 256 + (cc ^ (dl & 7)) * 8);
        #pragma unroll
        for (int it = 0; it < 16; it++) {
            bf16x8 bfr = *(const bf16x8*)(out_t + (size_t)(b * NN + i0 + it * 16 + l15) * CC + kk * 32 + g * 8);
            MFMA16(acc[it], af, bfr);
        }
    }
    int dbase = d0 + w * 16 + g * 4;
    f32x4 pb = *(const f32x4*)(proj_b + dbase);
    #pragma unroll
    for (int it = 0; it < 16; it++) {
        int i = i0 + it * 16 + l15;
        #pragma unroll
        for (int e = 0; e < 4; e++) {
            int off = (b * CC + dbase + e) * NN + i;
            out[off] = acc[it][e] + pb[e] + x[off];
        }
    }
}

extern "C" void kernel_launch(void* const* d_in, const int* in_sizes, int n_in,
                              void* d_out, int out_size, void* d_ws, size_t ws_size,
                              hipStream_t stream) {
    const float* x      = (const float*)d_in[0];
    const float* gamma  = (const float*)d_in[1];
    const float* beta   = (const float*)d_in[2];
    const float* qkv_w  = (const float*)d_in[3];
    const float* qkv_b  = (const float*)d_in[4];
    const float* proj_w = (const float*)d_in[5];
    const float* proj_b = (const float*)d_in[6];
    float* out = (float*)d_out;

    char* ws = (char*)d_ws;
    float* part   = (float*)ws;                       // 2048 B
    ushort* wq    = (ushort*)(ws + 4096);             // 384 KiB
    ushort* wp    = (ushort*)(ws + 4096 + 393216);    // 128 KiB -> ends 528384
    ushort* xn_t  = (ushort*)(ws + 528384);
    ushort* q_t   = (ushort*)(ws + 528384 + 1ull * 8388608);
    ushort* k_t   = (ushort*)(ws + 528384 + 2ull * 8388608);
    ushort* v_g   = (ushort*)(ws + 528384 + 3ull * 8388608);
    ushort* out_t = xn_t;

    size_t mlbase = 528384 + 4ull * 8388608;
    float* l_part = (float*)(ws + mlbase);
    size_t obase  = mlbase + 1048576;
    ushort* On    = (ushort*)(ws + obase);            // S * 8 MiB (fp16 normalized)

    int S = 1;
    if (ws_size >= obase + 4ull * 8388608) S = 4;
    else if (ws_size >= obase + 2ull * 8388608) S = 2;
    int nwg = 16 * S * BB;

    stats_prep<<<dim3(64, 5), 256, 0, stream>>>(x, part, qkv_w, proj_w, wq, wp);
    norm_t_kernel<<<dim3(128, 8, 4), 256, 0, stream>>>(x, gamma, beta, part, xn_t);
    qkv_kernel<<<dim3(2, 64, 4), 256, 0, stream>>>(xn_t, wq, qkv_b, q_t, k_t, v_g);
    flash_kernel<<<nwg, 512, 0, stream>>>(q_t, k_t, v_g, On, l_part, NN / S, S, nwg);
    merge_kernel<<<4096, 256, 0, stream>>>(On, l_part, out_t, S);
    proj_kernel<<<dim3(4, 16, 4), 256, 0, stream>>>(out_t, wp, proj_b, x, out);
}

// Round 23
// 168.546 us; speedup vs baseline: 1.0033x; 1.0002x over previous
//
#include <hip/hip_runtime.h>
#include <hip/hip_fp16.h>

#define BB 4
#define CC 256
#define NN 4096
#define CNT (CC*NN)
#define VLD 40   // padded V row stride (ushorts): banks de-alias (80B rows)

typedef float f32x4 __attribute__((ext_vector_type(4)));
typedef short bf16x8 __attribute__((ext_vector_type(8)));

__device__ inline ushort f2bf(float f) {
    union { float f; uint u; } v; v.f = f;
    uint r = v.u + 0x7fff + ((v.u >> 16) & 1);
    return (ushort)(r >> 16);
}

__device__ inline ushort f2h(float f) {
    __half h = __float2half(f);
    return *(ushort*)&h;
}

__device__ inline float h2f(ushort u) {
    __half h = *(__half*)&u;
    return __half2float(h);
}

__device__ inline uint cvt_pk_bf16(float a, float b) {
    uint r;
    asm("v_cvt_pk_bf16_f32 %0, %1, %2" : "=v"(r) : "v"(a), "v"(b));
    return r;
}

#define MFMA16(d, a, b) d = __builtin_amdgcn_mfma_f32_16x16x32_bf16(a, b, d, 0, 0, 0)

// sigma: inverse of the PV contraction permutation pi (within a 32-token tile).
__device__ inline int sigma32(int j) {
    return (j < 16) ? (((j >> 2) << 3) + (j & 3))
                    : ((((j - 16) >> 2) << 3) + ((j - 16) & 3) + 4);
}

// ---------------- stats (y<4) + weight prep (y==4), fused ----------------
__global__ __launch_bounds__(256) void stats_prep(
    const float* __restrict__ x, float* __restrict__ part,
    const float* __restrict__ qkv_w, const float* __restrict__ proj_w,
    ushort* __restrict__ wq, ushort* __restrict__ wp)
{
    if (blockIdx.y == 4) {
        int tid = blockIdx.x * 256 + threadIdx.x;      // 0..16383
        #pragma unroll
        for (int k = 0; k < 4; k++) {
            int idx = tid + k * 16384;                 // 0..65535
            if (idx < 49152) {
                int row = (idx * 4) >> 8;
                float sc = (row < 256) ? 0.0625f * 1.4426950408889634f : 1.0f;
                f32x4 v = *(const f32x4*)(qkv_w + (size_t)idx * 4);
                ushort4 o;
                o.x = f2bf(v.x * sc); o.y = f2bf(v.y * sc);
                o.z = f2bf(v.z * sc); o.w = f2bf(v.w * sc);
                *(ushort4*)(wq + (size_t)idx * 4) = o;
            } else {
                int j = idx - 49152;
                f32x4 v = *(const f32x4*)(proj_w + (size_t)j * 4);
                ushort4 o;
                o.x = f2bf(v.x); o.y = f2bf(v.y); o.z = f2bf(v.z); o.w = f2bf(v.w);
                *(ushort4*)(wp + (size_t)j * 4) = o;
            }
        }
        return;
    }
    int b = blockIdx.y;
    const float* xb = x + b * CNT;
    float s = 0.f, q = 0.f;
    int base = (blockIdx.x * 256 + threadIdx.x) * 4;
    for (int i = base; i < CNT; i += 64 * 256 * 4) {
        f32x4 v = *(const f32x4*)(xb + i);
        s += (v.x + v.y) + (v.z + v.w);
        q += (v.x * v.x + v.y * v.y) + (v.z * v.z + v.w * v.w);
    }
    for (int off = 32; off; off >>= 1) {
        s += __shfl_down(s, off, 64);
        q += __shfl_down(q, off, 64);
    }
    __shared__ float red[8];
    int lane = threadIdx.x & 63, wv = threadIdx.x >> 6;
    if (!lane) { red[wv * 2] = s; red[wv * 2 + 1] = q; }
    __syncthreads();
    if (threadIdx.x == 0) {
        part[(b * 64 + blockIdx.x) * 2 + 0] = red[0] + red[2] + red[4] + red[6];
        part[(b * 64 + blockIdx.x) * 2 + 1] = red[1] + red[3] + red[5] + red[7];
    }
}

// ---------------- norm + transpose (final stats reduce inlined per block) ----------------
__global__ __launch_bounds__(256) void norm_t_kernel(
    const float* __restrict__ x, const float* __restrict__ gamma,
    const float* __restrict__ beta, const float* __restrict__ part,
    ushort* __restrict__ xn_t)
{
    int b = blockIdx.z;
    __shared__ float mv[2];
    if (threadIdx.x < 64) {
        float s = part[(b * 64 + threadIdx.x) * 2 + 0];
        float q = part[(b * 64 + threadIdx.x) * 2 + 1];
        for (int off = 32; off; off >>= 1) {
            s += __shfl_down(s, off, 64);
            q += __shfl_down(q, off, 64);
        }
        if (threadIdx.x == 0) {
            float mean = s * (1.0f / (float)CNT);
            float var = q * (1.0f / (float)CNT) - mean * mean;
            mv[0] = mean;
            mv[1] = rsqrtf(var + 1e-5f);
        }
    }
    __syncthreads();
    float mean = mv[0], rinv = mv[1];

    int n0 = blockIdx.x * 32, c0 = blockIdx.y * 32;
    __shared__ float tl[32][33];
    int tr = threadIdx.x >> 3;
    int tc4 = (threadIdx.x & 7) * 4;
    int c = c0 + tr;
    float gsc = gamma[c] * rinv;
    float bsc = beta[c] - mean * gsc;
    f32x4 v = *(const f32x4*)(x + ((b * CC + c) * NN + n0 + tc4));
    tl[tr][tc4 + 0] = v.x * gsc + bsc;
    tl[tr][tc4 + 1] = v.y * gsc + bsc;
    tl[tr][tc4 + 2] = v.z * gsc + bsc;
    tl[tr][tc4 + 3] = v.w * gsc + bsc;
    __syncthreads();
    int nr = threadIdx.x >> 3;
    int cg4 = (threadIdx.x & 7) * 4;
    ushort4 o;
    o.x = f2bf(tl[cg4 + 0][nr]);
    o.y = f2bf(tl[cg4 + 1][nr]);
    o.z = f2bf(tl[cg4 + 2][nr]);
    o.w = f2bf(tl[cg4 + 3][nr]);
    *(ushort4*)(xn_t + ((size_t)(b * NN + n0 + nr) * CC + c0 + cg4)) = o;
}

// ---------------- QKV GEMM: bf16 weights; V written PERMUTED (sigma within 32-tiles) ----------------
__global__ __launch_bounds__(256) void qkv_kernel(
    const ushort* __restrict__ xn_t, const ushort* __restrict__ wq,
    const float* __restrict__ qkv_b, ushort* __restrict__ q_t,
    ushort* __restrict__ k_t, ushort* __restrict__ v_g)
{
    int b = blockIdx.z;
    int i0 = blockIdx.y * 64;
    int t = threadIdx.x, w = t >> 6, l = t & 63, l15 = l & 15, g = l >> 4;
    __shared__ ushort b_lds[64 * 256];

    #pragma unroll
    for (int it = 0; it < 8; it++) {
        int cid = it * 256 + t;
        int rr = cid >> 5, cc = cid & 31;
        bf16x8 vv = *(const bf16x8*)(xn_t + ((size_t)(b * NN + i0 + rr) * CC + cc * 8));
        *(bf16x8*)(b_lds + rr * 256 + (cc ^ (rr & 7)) * 8) = vv;
    }
    __syncthreads();

    for (int ds = 0; ds < 6; ds++) {
        int d0 = blockIdx.x * 384 + ds * 64;
        int drow = d0 + w * 16 + l15;
        bf16x8 af[8];
        #pragma unroll
        for (int kk = 0; kk < 8; kk++)
            af[kk] = *(const bf16x8*)(wq + (size_t)drow * CC + kk * 32 + g * 8);

        f32x4 acc[4];
        #pragma unroll
        for (int it = 0; it < 4; it++) { f32x4 z = {0.f, 0.f, 0.f, 0.f}; acc[it] = z; }
        #pragma unroll
        for (int kk = 0; kk < 8; kk++) {
            int cc = kk * 4 + g;
            #pragma unroll
            for (int it = 0; it < 4; it++) {
                int il = it * 16 + l15;
                bf16x8 bf = *(const bf16x8*)(b_lds + il * 256 + (cc ^ (il & 7)) * 8);
                MFMA16(acc[it], af[kk], bf);
            }
        }
        int dbase = d0 + w * 16 + g * 4;
        f32x4 bias = *(const f32x4*)(qkv_b + dbase);
        float bs = (d0 < 256) ? 0.0625f * 1.4426950408889634f : 1.0f;
        #pragma unroll
        for (int it = 0; it < 4; it++) {
            int i = i0 + it * 16 + l15;
            if (d0 < 512) {
                ushort4 o;
                o.x = f2bf(acc[it][0] + bias[0] * bs);
                o.y = f2bf(acc[it][1] + bias[1] * bs);
                o.z = f2bf(acc[it][2] + bias[2] * bs);
                o.w = f2bf(acc[it][3] + bias[3] * bs);
                ushort* dst = (d0 < 256) ? q_t : k_t;
                int dl = dbase - ((d0 < 256) ? 0 : 256);
                *(ushort4*)(dst + ((size_t)(b * NN + i) * CC + dl)) = o;
            } else {
                int ip = (i & ~31) | sigma32(i & 31);
                #pragma unroll
                for (int e = 0; e < 4; e++)
                    v_g[(size_t)(b * CC + (dbase - 512 + e)) * NN + ip] = f2bf(acc[it][e] + bias[e]);
            }
        }
    }
}

// ---------------- flash attention: zero-shuffle PV, padded V LDS (80B rows) ----------------
__global__ __launch_bounds__(512, 2) void flash_kernel(
    const ushort* __restrict__ q_t, const ushort* __restrict__ k_t,
    const ushort* __restrict__ v_g, ushort* __restrict__ On,
    float* __restrict__ l_part, int segn, int S, int nwg)
{
    int bid = blockIdx.x;
    int L = (bid & 7) * (nwg >> 3) + (bid >> 3);   // bijective (nwg % 8 == 0)
    int i0 = (L & 15) * 256;
    int seg = (L >> 4) % S;
    int b = L / (16 * S);
    int jbase = seg * segn;
    int t = threadIdx.x, w = t >> 6, l = t & 63, l15 = l & 15, g = l >> 4;

    __shared__ ushort k_lds[2][32 * 256];   // [j][16B chunk ^ (j&7)]
    __shared__ ushort v_lds[2][256 * VLD];  // [c][16B chunk ^ s4(c)], 80B row pitch

    bf16x8 qf0[8], qf1[8];
    const ushort* qr0 = q_t + (size_t)(b * NN + i0 + w * 32 + l15) * CC + g * 8;
    #pragma unroll
    for (int kk = 0; kk < 8; kk++) qf0[kk] = *(const bf16x8*)(qr0 + kk * 32);
    const ushort* qr1 = qr0 + (size_t)16 * CC;
    #pragma unroll
    for (int kk = 0; kk < 8; kk++) qf1[kk] = *(const bf16x8*)(qr1 + kk * 32);

    f32x4 O0[16], O1[16];
    #pragma unroll
    for (int tc = 0; tc < 16; tc++) {
        f32x4 z = {0.f, 0.f, 0.f, 0.f};
        O0[tc] = z; O1[tc] = z;
    }
    float l0 = 0.f, l1 = 0.f;

    const ushort* kb = k_t + (size_t)b * NN * CC;
    const ushort* vb = v_g + (size_t)b * CC * NN;

    auto stage_tile = [&](int d, int jt) {
        bf16x8 kr[2], vr[2];
        #pragma unroll
        for (int is = 0; is < 2; is++) {
            int s = is * 512 + t;
            kr[is] = *(const bf16x8*)(kb + (size_t)(jt + (s >> 5)) * CC + (s & 31) * 8);
            vr[is] = *(const bf16x8*)(vb + (size_t)(s >> 2) * NN + jt + (s & 3) * 8);
        }
        #pragma unroll
        for (int is = 0; is < 2; is++) {
            int s = is * 512 + t;
            int jr = s >> 5, cc = s & 31;
            *(bf16x8*)((ushort*)k_lds[d] + jr * 256 + ((cc ^ (jr & 7)) * 8)) = kr[is];
            int cr = s >> 2, cv = s & 3;
            *(bf16x8*)((ushort*)v_lds[d] + cr * VLD + ((cv ^ ((cr ^ (cr >> 2)) & 3)) * 8)) = vr[is];
        }
    };

    stage_tile(0, jbase);
    int niter = segn >> 5;

    for (int it = 0; it < niter; it++) {
        int d = it & 1;
        __syncthreads();
        const ushort* kl = k_lds[d];
        const ushort* vl = v_lds[d];

        // S^T = K Q^T, 4 independent chains (2 jg x 2 rb) sharing bk loads.
        f32x4 s00 = {0.f, 0.f, 0.f, 0.f}, s01 = s00, s10 = s00, s11 = s00;
        {
            const ushort* krow = kl + l15 * 256;
            int xj = l15 & 7;
            #pragma unroll
            for (int kk = 0; kk < 8; kk++) {
                int off = ((kk * 4 + g) ^ xj) * 8;
                bf16x8 bk0 = *(const bf16x8*)(krow + off);
                bf16x8 bk1 = *(const bf16x8*)(krow + 16 * 256 + off);
                MFMA16(s00, bk0, qf0[kk]);
                MFMA16(s10, bk0, qf1[kk]);
                MFMA16(s01, bk1, qf0[kk]);
                MFMA16(s11, bk1, qf1[kk]);
            }
        }

        // softmax: p = exp2(S); pack P directly as A-fragment (permuted-V contraction)
        union { bf16x8 v; uint u[4]; } pa0, pa1;
        {
            float a0 = exp2f(s00[0]), a1 = exp2f(s00[1]);
            float a2 = exp2f(s00[2]), a3 = exp2f(s00[3]);
            float a4 = exp2f(s01[0]), a5 = exp2f(s01[1]);
            float a6 = exp2f(s01[2]), a7 = exp2f(s01[3]);
            l0 += ((a0 + a1) + (a2 + a3)) + ((a4 + a5) + (a6 + a7));
            pa0.u[0] = cvt_pk_bf16(a0, a1); pa0.u[1] = cvt_pk_bf16(a2, a3);
            pa0.u[2] = cvt_pk_bf16(a4, a5); pa0.u[3] = cvt_pk_bf16(a6, a7);
            float b0 = exp2f(s10[0]), b1 = exp2f(s10[1]);
            float b2 = exp2f(s10[2]), b3 = exp2f(s10[3]);
            float b4 = exp2f(s11[0]), b5 = exp2f(s11[1]);
            float b6 = exp2f(s11[2]), b7 = exp2f(s11[3]);
            l1 += ((b0 + b1) + (b2 + b3)) + ((b4 + b5) + (b6 + b7));
            pa1.u[0] = cvt_pk_bf16(b0, b1); pa1.u[1] = cvt_pk_bf16(b2, b3);
            pa1.u[2] = cvt_pk_bf16(b4, b5); pa1.u[3] = cvt_pk_bf16(b6, b7);
        }

        // O += P V^T: B-fragment = contiguous b128 (chunk g) of permuted V
        #pragma unroll
        for (int tc = 0; tc < 16; tc++) {
            int c = tc * 16 + l15;
            bf16x8 vf = *(const bf16x8*)(vl + c * VLD + ((g ^ ((c ^ (c >> 2)) & 3)) * 8));
            MFMA16(O0[tc], pa0.v, vf);
            MFMA16(O1[tc], pa1.v, vf);
        }

        if (it + 1 < niter) stage_tile(d ^ 1, jbase + (it + 1) * 32);
    }

    // l lives per (l15): reduce across the 4 g-groups
    l0 += __shfl_xor(l0, 16, 64); l1 += __shfl_xor(l1, 16, 64);
    l0 += __shfl_xor(l0, 32, 64); l1 += __shfl_xor(l1, 32, 64);

    size_t obase = (size_t)(seg * BB + b) * NN + i0;
    if (g == 0) {
        l_part[obase + w * 32 + l15] = l0;
        l_part[obase + w * 32 + 16 + l15] = l1;
    }
    #pragma unroll
    for (int e = 0; e < 4; e++) {
        int ro = w * 32 + g * 4 + e;
        float inv0 = 1.0f / __shfl(l0, g * 4 + e, 64);
        float inv1 = 1.0f / __shfl(l1, g * 4 + e, 64);
        ushort* orow0 = On + (obase + ro) * CC + l15;
        ushort* orow1 = On + (obase + ro + 16) * CC + l15;
        #pragma unroll
        for (int tc = 0; tc < 16; tc++) {
            orow0[tc * 16] = f2h(O0[tc][e] * inv0);
            orow1[tc * 16] = f2h(O1[tc][e] * inv1);
        }
    }
}

// ---------------- merge: out = (sum_s l_s * O_s_norm) / (sum_s l_s), fp16 in, bf16 out ----------------
__global__ __launch_bounds__(256) void merge_kernel(
    const ushort* __restrict__ On, const float* __restrict__ l_part,
    ushort* __restrict__ out_t, int S)
{
    int idx = blockIdx.x * 256 + threadIdx.x;
    int row = idx >> 6;
    float lsum = 0.f;
    float a0 = 0.f, a1 = 0.f, a2 = 0.f, a3 = 0.f;
    for (int s = 0; s < S; s++) {
        float ls = l_part[(size_t)s * BB * NN + row];
        lsum += ls;
        ushort4 v = *(const ushort4*)(On + (size_t)s * BB * NN * CC + (size_t)idx * 4);
        a0 += ls * h2f(v.x);
        a1 += ls * h2f(v.y);
        a2 += ls * h2f(v.z);
        a3 += ls * h2f(v.w);
    }
    float inv = 1.0f / lsum;
    ushort4 o;
    o.x = f2bf(a0 * inv);
    o.y = f2bf(a1 * inv);
    o.z = f2bf(a2 * inv);
    o.w = f2bf(a3 * inv);
    *(ushort4*)(out_t + (size_t)idx * 4) = o;
}

// ---------------- proj GEMM + bias + residual (bf16 weights) ----------------
__global__ __launch_bounds__(256) void proj_kernel(
    const ushort* __restrict__ out_t, const ushort* __restrict__ wp,
    const float* __restrict__ proj_b, const float* __restrict__ x,
    float* __restrict__ out)
{
    int b = blockIdx.z;
    int d0 = blockIdx.x * 64;
    int i0 = blockIdx.y * 256;
    int t = threadIdx.x, w = t >> 6, l = t & 63, l15 = l & 15, g = l >> 4;
    __shared__ ushort a_lds[64 * 256];

    #pragma unroll
    for (int it = 0; it < 8; it++) {
        int cid = it * 256 + t;
        int dd = cid >> 5, cc = cid & 31;
        bf16x8 a = *(const bf16x8*)(wp + (size_t)(d0 + dd) * CC + cc * 8);
        *(bf16x8*)(a_lds + dd * 256 + (cc ^ (dd & 7)) * 8) = a;
    }
    __syncthreads();

    f32x4 acc[16];
    #pragma unroll
    for (int it = 0; it < 16; it++) { f32x4 z = {0.f, 0.f, 0.f, 0.f}; acc[it] = z; }
    int dl = w * 16 + l15;
    #pragma unroll
    for (int kk = 0; kk < 8; kk++) {
        int cc = kk * 4 + g;
        bf16x8 af = *(const bf16x8*)(a_lds + dl * 256 + (cc ^ (dl & 7)) * 8);
        #pragma unroll
        for (int it = 0; it < 16; it++) {
            bf16x8 bfr = *(const bf16x8*)(out_t + (size_t)(b * NN + i0 + it * 16 + l15) * CC + kk * 32 + g * 8);
            MFMA16(acc[it], af, bfr);
        }
    }
    int dbase = d0 + w * 16 + g * 4;
    f32x4 pb = *(const f32x4*)(proj_b + dbase);
    #pragma unroll
    for (int it = 0; it < 16; it++) {
        int i = i0 + it * 16 + l15;
        #pragma unroll
        for (int e = 0; e < 4; e++) {
            int off = (b * CC + dbase + e) * NN + i;
            out[off] = acc[it][e] + pb[e] + x[off];
        }
    }
}

extern "C" void kernel_launch(void* const* d_in, const int* in_sizes, int n_in,
                              void* d_out, int out_size, void* d_ws, size_t ws_size,
                              hipStream_t stream) {
    const float* x      = (const float*)d_in[0];
    const float* gamma  = (const float*)d_in[1];
    const float* beta   = (const float*)d_in[2];
    const float* qkv_w  = (const float*)d_in[3];
    const float* qkv_b  = (const float*)d_in[4];
    const float* proj_w = (const float*)d_in[5];
    const float* proj_b = (const float*)d_in[6];
    float* out = (float*)d_out;

    char* ws = (char*)d_ws;
    float* part   = (float*)ws;                       // 2048 B
    ushort* wq    = (ushort*)(ws + 4096);             // 384 KiB
    ushort* wp    = (ushort*)(ws + 4096 + 393216);    // 128 KiB -> ends 528384
    ushort* xn_t  = (ushort*)(ws + 528384);
    ushort* q_t   = (ushort*)(ws + 528384 + 1ull * 8388608);
    ushort* k_t   = (ushort*)(ws + 528384 + 2ull * 8388608);
    ushort* v_g   = (ushort*)(ws + 528384 + 3ull * 8388608);
    ushort* out_t = xn_t;

    size_t mlbase = 528384 + 4ull * 8388608;
    float* l_part = (float*)(ws + mlbase);
    size_t obase  = mlbase + 1048576;
    ushort* On    = (ushort*)(ws + obase);            // S * 8 MiB (fp16 normalized)

    int S = 1;
    if (ws_size >= obase + 4ull * 8388608) S = 4;
    else if (ws_size >= obase + 2ull * 8388608) S = 2;
    int nwg = 16 * S * BB;

    stats_prep<<<dim3(64, 5), 256, 0, stream>>>(x, part, qkv_w, proj_w, wq, wp);
    norm_t_kernel<<<dim3(128, 8, 4), 256, 0, stream>>>(x, gamma, beta, part, xn_t);
    qkv_kernel<<<dim3(2, 64, 4), 256, 0, stream>>>(xn_t, wq, qkv_b, q_t, k_t, v_g);
    flash_kernel<<<nwg, 512, 0, stream>>>(q_t, k_t, v_g, On, l_part, NN / S, S, nwg);
    merge_kernel<<<4096, 256, 0, stream>>>(On, l_part, out_t, S);
    proj_kernel<<<dim3(4, 16, 4), 256, 0, stream>>>(out_t, wp, proj_b, x, out);
}

// Round 24
// 164.128 us; speedup vs baseline: 1.0304x; 1.0269x over previous
//
#include <hip/hip_runtime.h>
#include <hip/hip_fp16.h>

#define BB 4
#define CC 256
#define NN 4096
#define CNT (CC*NN)

typedef float f32x4 __attribute__((ext_vector_type(4)));
typedef short bf16x8 __attribute__((ext_vector_type(8)));

__device__ inline ushort f2bf(float f) {
    union { float f; uint u; } v; v.f = f;
    uint r = v.u + 0x7fff + ((v.u >> 16) & 1);
    return (ushort)(r >> 16);
}

__device__ inline ushort f2h(float f) {
    __half h = __float2half(f);
    return *(ushort*)&h;
}

__device__ inline float h2f(ushort u) {
    __half h = *(__half*)&u;
    return __half2float(h);
}

__device__ inline uint cvt_pk_bf16(float a, float b) {
    uint r;
    asm("v_cvt_pk_bf16_f32 %0, %1, %2" : "=v"(r) : "v"(a), "v"(b));
    return r;
}

#define MFMA16(d, a, b) d = __builtin_amdgcn_mfma_f32_16x16x32_bf16(a, b, d, 0, 0, 0)

// sigma: inverse of the PV contraction permutation pi (within a 32-token tile).
__device__ inline int sigma32(int j) {
    return (j < 16) ? (((j >> 2) << 3) + (j & 3))
                    : ((((j - 16) >> 2) << 3) + ((j - 16) & 3) + 4);
}

// ---------------- stats (y<4) + weight prep (y==4), fused ----------------
__global__ __launch_bounds__(256) void stats_prep(
    const float* __restrict__ x, float* __restrict__ part,
    const float* __restrict__ qkv_w, const float* __restrict__ proj_w,
    ushort* __restrict__ wq, ushort* __restrict__ wp)
{
    if (blockIdx.y == 4) {
        int tid = blockIdx.x * 256 + threadIdx.x;      // 0..16383
        #pragma unroll
        for (int k = 0; k < 4; k++) {
            int idx = tid + k * 16384;                 // 0..65535
            if (idx < 49152) {
                int row = (idx * 4) >> 8;
                float sc = (row < 256) ? 0.0625f * 1.4426950408889634f : 1.0f;
                f32x4 v = *(const f32x4*)(qkv_w + (size_t)idx * 4);
                ushort4 o;
                o.x = f2bf(v.x * sc); o.y = f2bf(v.y * sc);
                o.z = f2bf(v.z * sc); o.w = f2bf(v.w * sc);
                *(ushort4*)(wq + (size_t)idx * 4) = o;
            } else {
                int j = idx - 49152;
                f32x4 v = *(const f32x4*)(proj_w + (size_t)j * 4);
                ushort4 o;
                o.x = f2bf(v.x); o.y = f2bf(v.y); o.z = f2bf(v.z); o.w = f2bf(v.w);
                *(ushort4*)(wp + (size_t)j * 4) = o;
            }
        }
        return;
    }
    int b = blockIdx.y;
    const float* xb = x + b * CNT;
    float s = 0.f, q = 0.f;
    int base = (blockIdx.x * 256 + threadIdx.x) * 4;
    for (int i = base; i < CNT; i += 64 * 256 * 4) {
        f32x4 v = *(const f32x4*)(xb + i);
        s += (v.x + v.y) + (v.z + v.w);
        q += (v.x * v.x + v.y * v.y) + (v.z * v.z + v.w * v.w);
    }
    for (int off = 32; off; off >>= 1) {
        s += __shfl_down(s, off, 64);
        q += __shfl_down(q, off, 64);
    }
    __shared__ float red[8];
    int lane = threadIdx.x & 63, wv = threadIdx.x >> 6;
    if (!lane) { red[wv * 2] = s; red[wv * 2 + 1] = q; }
    __syncthreads();
    if (threadIdx.x == 0) {
        part[(b * 64 + blockIdx.x) * 2 + 0] = red[0] + red[2] + red[4] + red[6];
        part[(b * 64 + blockIdx.x) * 2 + 1] = red[1] + red[3] + red[5] + red[7];
    }
}

// ---------------- norm + transpose (final stats reduce inlined per block) ----------------
__global__ __launch_bounds__(256) void norm_t_kernel(
    const float* __restrict__ x, const float* __restrict__ gamma,
    const float* __restrict__ beta, const float* __restrict__ part,
    ushort* __restrict__ xn_t)
{
    int b = blockIdx.z;
    __shared__ float mv[2];
    if (threadIdx.x < 64) {
        float s = part[(b * 64 + threadIdx.x) * 2 + 0];
        float q = part[(b * 64 + threadIdx.x) * 2 + 1];
        for (int off = 32; off; off >>= 1) {
            s += __shfl_down(s, off, 64);
            q += __shfl_down(q, off, 64);
        }
        if (threadIdx.x == 0) {
            float mean = s * (1.0f / (float)CNT);
            float var = q * (1.0f / (float)CNT) - mean * mean;
            mv[0] = mean;
            mv[1] = rsqrtf(var + 1e-5f);
        }
    }
    __syncthreads();
    float mean = mv[0], rinv = mv[1];

    int n0 = blockIdx.x * 32, c0 = blockIdx.y * 32;
    __shared__ float tl[32][33];
    int tr = threadIdx.x >> 3;
    int tc4 = (threadIdx.x & 7) * 4;
    int c = c0 + tr;
    float gsc = gamma[c] * rinv;
    float bsc = beta[c] - mean * gsc;
    f32x4 v = *(const f32x4*)(x + ((b * CC + c) * NN + n0 + tc4));
    tl[tr][tc4 + 0] = v.x * gsc + bsc;
    tl[tr][tc4 + 1] = v.y * gsc + bsc;
    tl[tr][tc4 + 2] = v.z * gsc + bsc;
    tl[tr][tc4 + 3] = v.w * gsc + bsc;
    __syncthreads();
    int nr = threadIdx.x >> 3;
    int cg4 = (threadIdx.x & 7) * 4;
    ushort4 o;
    o.x = f2bf(tl[cg4 + 0][nr]);
    o.y = f2bf(tl[cg4 + 1][nr]);
    o.z = f2bf(tl[cg4 + 2][nr]);
    o.w = f2bf(tl[cg4 + 3][nr]);
    *(ushort4*)(xn_t + ((size_t)(b * NN + n0 + nr) * CC + c0 + cg4)) = o;
}

// ---------------- QKV GEMM: bf16 weights; V written PERMUTED (sigma within 32-tiles) ----------------
__global__ __launch_bounds__(256) void qkv_kernel(
    const ushort* __restrict__ xn_t, const ushort* __restrict__ wq,
    const float* __restrict__ qkv_b, ushort* __restrict__ q_t,
    ushort* __restrict__ k_t, ushort* __restrict__ v_g)
{
    int b = blockIdx.z;
    int i0 = blockIdx.y * 64;
    int t = threadIdx.x, w = t >> 6, l = t & 63, l15 = l & 15, g = l >> 4;
    __shared__ ushort b_lds[64 * 256];

    #pragma unroll
    for (int it = 0; it < 8; it++) {
        int cid = it * 256 + t;
        int rr = cid >> 5, cc = cid & 31;
        bf16x8 vv = *(const bf16x8*)(xn_t + ((size_t)(b * NN + i0 + rr) * CC + cc * 8));
        *(bf16x8*)(b_lds + rr * 256 + (cc ^ (rr & 7)) * 8) = vv;
    }
    __syncthreads();

    for (int ds = 0; ds < 6; ds++) {
        int d0 = blockIdx.x * 384 + ds * 64;
        int drow = d0 + w * 16 + l15;
        bf16x8 af[8];
        #pragma unroll
        for (int kk = 0; kk < 8; kk++)
            af[kk] = *(const bf16x8*)(wq + (size_t)drow * CC + kk * 32 + g * 8);

        f32x4 acc[4];
        #pragma unroll
        for (int it = 0; it < 4; it++) { f32x4 z = {0.f, 0.f, 0.f, 0.f}; acc[it] = z; }
        #pragma unroll
        for (int kk = 0; kk < 8; kk++) {
            int cc = kk * 4 + g;
            #pragma unroll
            for (int it = 0; it < 4; it++) {
                int il = it * 16 + l15;
                bf16x8 bf = *(const bf16x8*)(b_lds + il * 256 + (cc ^ (il & 7)) * 8);
                MFMA16(acc[it], af[kk], bf);
            }
        }
        int dbase = d0 + w * 16 + g * 4;
        f32x4 bias = *(const f32x4*)(qkv_b + dbase);
        float bs = (d0 < 256) ? 0.0625f * 1.4426950408889634f : 1.0f;
        #pragma unroll
        for (int it = 0; it < 4; it++) {
            int i = i0 + it * 16 + l15;
            if (d0 < 512) {
                ushort4 o;
                o.x = f2bf(acc[it][0] + bias[0] * bs);
                o.y = f2bf(acc[it][1] + bias[1] * bs);
                o.z = f2bf(acc[it][2] + bias[2] * bs);
                o.w = f2bf(acc[it][3] + bias[3] * bs);
                ushort* dst = (d0 < 256) ? q_t : k_t;
                int dl = dbase - ((d0 < 256) ? 0 : 256);
                *(ushort4*)(dst + ((size_t)(b * NN + i) * CC + dl)) = o;
            } else {
                int ip = (i & ~31) | sigma32(i & 31);
                #pragma unroll
                for (int e = 0; e < 4; e++)
                    v_g[(size_t)(b * CC + (dbase - 512 + e)) * NN + ip] = f2bf(acc[it][e] + bias[e]);
            }
        }
    }
}

// ---------------- flash attention: zero-shuffle PV via permuted V, XCD-grouped grid ----------------
__global__ __launch_bounds__(512, 2) void flash_kernel(
    const ushort* __restrict__ q_t, const ushort* __restrict__ k_t,
    const ushort* __restrict__ v_g, ushort* __restrict__ On,
    float* __restrict__ l_part, int segn, int S, int nwg)
{
    int bid = blockIdx.x;
    int L = (bid & 7) * (nwg >> 3) + (bid >> 3);   // bijective (nwg % 8 == 0)
    int i0 = (L & 15) * 256;
    int seg = (L >> 4) % S;
    int b = L / (16 * S);
    int jbase = seg * segn;
    int t = threadIdx.x, w = t >> 6, l = t & 63, l15 = l & 15, g = l >> 4;

    __shared__ ushort k_lds[2][32 * 256];  // [j][16B chunk ^ (j&7)]
    __shared__ ushort v_lds[2][256 * 32];  // [c][16B chunk ^ s4(c)] (perm'd tokens)

    bf16x8 qf0[8], qf1[8];
    const ushort* qr0 = q_t + (size_t)(b * NN + i0 + w * 32 + l15) * CC + g * 8;
    #pragma unroll
    for (int kk = 0; kk < 8; kk++) qf0[kk] = *(const bf16x8*)(qr0 + kk * 32);
    const ushort* qr1 = qr0 + (size_t)16 * CC;
    #pragma unroll
    for (int kk = 0; kk < 8; kk++) qf1[kk] = *(const bf16x8*)(qr1 + kk * 32);

    f32x4 O0[16], O1[16];
    #pragma unroll
    for (int tc = 0; tc < 16; tc++) {
        f32x4 z = {0.f, 0.f, 0.f, 0.f};
        O0[tc] = z; O1[tc] = z;
    }
    float l0 = 0.f, l1 = 0.f;

    const ushort* kb = k_t + (size_t)b * NN * CC;
    const ushort* vb = v_g + (size_t)b * CC * NN;

    auto stage_tile = [&](int d, int jt) {
        bf16x8 kr[2], vr[2];
        #pragma unroll
        for (int is = 0; is < 2; is++) {
            int s = is * 512 + t;
            kr[is] = *(const bf16x8*)(kb + (size_t)(jt + (s >> 5)) * CC + (s & 31) * 8);
            vr[is] = *(const bf16x8*)(vb + (size_t)(s >> 2) * NN + jt + (s & 3) * 8);
        }
        #pragma unroll
        for (int is = 0; is < 2; is++) {
            int s = is * 512 + t;
            int jr = s >> 5, cc = s & 31;
            *(bf16x8*)((ushort*)k_lds[d] + jr * 256 + ((cc ^ (jr & 7)) * 8)) = kr[is];
            int cr = s >> 2, cv = s & 3;
            *(bf16x8*)((ushort*)v_lds[d] + cr * 32 + ((cv ^ ((cr ^ (cr >> 2)) & 3)) * 8)) = vr[is];
        }
    };

    stage_tile(0, jbase);
    int niter = segn >> 5;

    for (int it = 0; it < niter; it++) {
        int d = it & 1;
        __syncthreads();
        const ushort* kl = k_lds[d];
        const ushort* vl = v_lds[d];

        // S^T = K Q^T, 4 independent chains (2 jg x 2 rb) sharing bk loads.
        f32x4 s00 = {0.f, 0.f, 0.f, 0.f}, s01 = s00, s10 = s00, s11 = s00;
        {
            const ushort* krow = kl + l15 * 256;
            int xj = l15 & 7;
            #pragma unroll
            for (int kk = 0; kk < 8; kk++) {
                int off = ((kk * 4 + g) ^ xj) * 8;
                bf16x8 bk0 = *(const bf16x8*)(krow + off);
                bf16x8 bk1 = *(const bf16x8*)(krow + 16 * 256 + off);
                MFMA16(s00, bk0, qf0[kk]);
                MFMA16(s10, bk0, qf1[kk]);
                MFMA16(s01, bk1, qf0[kk]);
                MFMA16(s11, bk1, qf1[kk]);
            }
        }

        // softmax: p = exp2(S); pack P directly as A-fragment (permuted-V contraction)
        union { bf16x8 v; uint u[4]; } pa0, pa1;
        {
            float a0 = exp2f(s00[0]), a1 = exp2f(s00[1]);
            float a2 = exp2f(s00[2]), a3 = exp2f(s00[3]);
            float a4 = exp2f(s01[0]), a5 = exp2f(s01[1]);
            float a6 = exp2f(s01[2]), a7 = exp2f(s01[3]);
            l0 += ((a0 + a1) + (a2 + a3)) + ((a4 + a5) + (a6 + a7));
            pa0.u[0] = cvt_pk_bf16(a0, a1); pa0.u[1] = cvt_pk_bf16(a2, a3);
            pa0.u[2] = cvt_pk_bf16(a4, a5); pa0.u[3] = cvt_pk_bf16(a6, a7);
            float b0 = exp2f(s10[0]), b1 = exp2f(s10[1]);
            float b2 = exp2f(s10[2]), b3 = exp2f(s10[3]);
            float b4 = exp2f(s11[0]), b5 = exp2f(s11[1]);
            float b6 = exp2f(s11[2]), b7 = exp2f(s11[3]);
            l1 += ((b0 + b1) + (b2 + b3)) + ((b4 + b5) + (b6 + b7));
            pa1.u[0] = cvt_pk_bf16(b0, b1); pa1.u[1] = cvt_pk_bf16(b2, b3);
            pa1.u[2] = cvt_pk_bf16(b4, b5); pa1.u[3] = cvt_pk_bf16(b6, b7);
        }

        // O += P V^T: B-fragment = contiguous b128 (chunk g) of permuted V
        #pragma unroll
        for (int tc = 0; tc < 16; tc++) {
            int c = tc * 16 + l15;
            bf16x8 vf = *(const bf16x8*)(vl + c * 32 + ((g ^ ((c ^ (c >> 2)) & 3)) * 8));
            MFMA16(O0[tc], pa0.v, vf);
            MFMA16(O1[tc], pa1.v, vf);
        }

        if (it + 1 < niter) stage_tile(d ^ 1, jbase + (it + 1) * 32);
    }

    // l lives per (l15): reduce across the 4 g-groups
    l0 += __shfl_xor(l0, 16, 64); l1 += __shfl_xor(l1, 16, 64);
    l0 += __shfl_xor(l0, 32, 64); l1 += __shfl_xor(l1, 32, 64);

    size_t obase = (size_t)(seg * BB + b) * NN + i0;
    if (g == 0) {
        l_part[obase + w * 32 + l15] = l0;
        l_part[obase + w * 32 + 16 + l15] = l1;
    }
    #pragma unroll
    for (int e = 0; e < 4; e++) {
        int ro = w * 32 + g * 4 + e;
        float inv0 = 1.0f / __shfl(l0, g * 4 + e, 64);
        float inv1 = 1.0f / __shfl(l1, g * 4 + e, 64);
        ushort* orow0 = On + (obase + ro) * CC + l15;
        ushort* orow1 = On + (obase + ro + 16) * CC + l15;
        #pragma unroll
        for (int tc = 0; tc < 16; tc++) {
            orow0[tc * 16] = f2h(O0[tc][e] * inv0);
            orow1[tc * 16] = f2h(O1[tc][e] * inv1);
        }
    }
}

// ---------------- merge: out = (sum_s l_s * O_s_norm) / (sum_s l_s), fp16 in, bf16 out ----------------
__global__ __launch_bounds__(256) void merge_kernel(
    const ushort* __restrict__ On, const float* __restrict__ l_part,
    ushort* __restrict__ out_t, int S)
{
    int idx = blockIdx.x * 256 + threadIdx.x;
    int row = idx >> 6;
    float lsum = 0.f;
    float a0 = 0.f, a1 = 0.f, a2 = 0.f, a3 = 0.f;
    for (int s = 0; s < S; s++) {
        float ls = l_part[(size_t)s * BB * NN + row];
        lsum += ls;
        ushort4 v = *(const ushort4*)(On + (size_t)s * BB * NN * CC + (size_t)idx * 4);
        a0 += ls * h2f(v.x);
        a1 += ls * h2f(v.y);
        a2 += ls * h2f(v.z);
        a3 += ls * h2f(v.w);
    }
    float inv = 1.0f / lsum;
    ushort4 o;
    o.x = f2bf(a0 * inv);
    o.y = f2bf(a1 * inv);
    o.z = f2bf(a2 * inv);
    o.w = f2bf(a3 * inv);
    *(ushort4*)(out_t + (size_t)idx * 4) = o;
}

// ---------------- proj GEMM + bias + residual (bf16 weights) ----------------
__global__ __launch_bounds__(256) void proj_kernel(
    const ushort* __restrict__ out_t, const ushort* __restrict__ wp,
    const float* __restrict__ proj_b, const float* __restrict__ x,
    float* __restrict__ out)
{
    int b = blockIdx.z;
    int d0 = blockIdx.x * 64;
    int i0 = blockIdx.y * 256;
    int t = threadIdx.x, w = t >> 6, l = t & 63, l15 = l & 15, g = l >> 4;
    __shared__ ushort a_lds[64 * 256];

    #pragma unroll
    for (int it = 0; it < 8; it++) {
        int cid = it * 256 + t;
        int dd = cid >> 5, cc = cid & 31;
        bf16x8 a = *(const bf16x8*)(wp + (size_t)(d0 + dd) * CC + cc * 8);
        *(bf16x8*)(a_lds + dd * 256 + (cc ^ (dd & 7)) * 8) = a;
    }
    __syncthreads();

    f32x4 acc[16];
    #pragma unroll
    for (int it = 0; it < 16; it++) { f32x4 z = {0.f, 0.f, 0.f, 0.f}; acc[it] = z; }
    int dl = w * 16 + l15;
    #pragma unroll
    for (int kk = 0; kk < 8; kk++) {
        int cc = kk * 4 + g;
        bf16x8 af = *(const bf16x8*)(a_lds + dl * 256 + (cc ^ (dl & 7)) * 8);
        #pragma unroll
        for (int it = 0; it < 16; it++) {
            bf16x8 bfr = *(const bf16x8*)(out_t + (size_t)(b * NN + i0 + it * 16 + l15) * CC + kk * 32 + g * 8);
            MFMA16(acc[it], af, bfr);
        }
    }
    int dbase = d0 + w * 16 + g * 4;
    f32x4 pb = *(const f32x4*)(proj_b + dbase);
    #pragma unroll
    for (int it = 0; it < 16; it++) {
        int i = i0 + it * 16 + l15;
        #pragma unroll
        for (int e = 0; e < 4; e++) {
            int off = (b * CC + dbase + e) * NN + i;
            out[off] = acc[it][e] + pb[e] + x[off];
        }
    }
}

extern "C" void kernel_launch(void* const* d_in, const int* in_sizes, int n_in,
                              void* d_out, int out_size, void* d_ws, size_t ws_size,
                              hipStream_t stream) {
    const float* x      = (const float*)d_in[0];
    const float* gamma  = (const float*)d_in[1];
    const float* beta   = (const float*)d_in[2];
    const float* qkv_w  = (const float*)d_in[3];
    const float* qkv_b  = (const float*)d_in[4];
    const float* proj_w = (const float*)d_in[5];
    const float* proj_b = (const float*)d_in[6];
    float* out = (float*)d_out;

    char* ws = (char*)d_ws;
    float* part   = (float*)ws;                       // 2048 B
    ushort* wq    = (ushort*)(ws + 4096);             // 384 KiB
    ushort* wp    = (ushort*)(ws + 4096 + 393216);    // 128 KiB -> ends 528384
    ushort* xn_t  = (ushort*)(ws + 528384);
    ushort* q_t   = (ushort*)(ws + 528384 + 1ull * 8388608);
    ushort* k_t   = (ushort*)(ws + 528384 + 2ull * 8388608);
    ushort* v_g   = (ushort*)(ws + 528384 + 3ull * 8388608);
    ushort* out_t = xn_t;

    size_t mlbase = 528384 + 4ull * 8388608;
    float* l_part = (float*)(ws + mlbase);
    size_t obase  = mlbase + 1048576;
    ushort* On    = (ushort*)(ws + obase);            // S * 8 MiB (fp16 normalized)

    int S = 1;
    if (ws_size >= obase + 4ull * 8388608) S = 4;
    else if (ws_size >= obase + 2ull * 8388608) S = 2;
    int nwg = 16 * S * BB;

    stats_prep<<<dim3(64, 5), 256, 0, stream>>>(x, part, qkv_w, proj_w, wq, wp);
    norm_t_kernel<<<dim3(128, 8, 4), 256, 0, stream>>>(x, gamma, beta, part, xn_t);
    qkv_kernel<<<dim3(2, 64, 4), 256, 0, stream>>>(xn_t, wq, qkv_b, q_t, k_t, v_g);
    flash_kernel<<<nwg, 512, 0, stream>>>(q_t, k_t, v_g, On, l_part, NN / S, S, nwg);
    merge_kernel<<<4096, 256, 0, stream>>>(On, l_part, out_t, S);
    proj_kernel<<<dim3(4, 16, 4), 256, 0, stream>>>(out_t, wp, proj_b, x, out);
}